// Round 7
// baseline (118.669 us; speedup 1.0000x reference)
//
#include <hip/hip_runtime.h>
#include <hip/hip_bf16.h>

// MPS log-trace: out[b] = log(trace(prod_{n=0..1023} A[s_idx[b,n]]))
//   Kernel 1: 256-entry table T[key] = A[b0]@...@A[b7] (fp32 in LDS), stored
//             bf16 as MFMA A-fragments with SIGMA-PERMUTED k-slots:
//             slot k of MFMA m carries logical row sg = (k&3)+8*((k>>2)&1)
//             +4*(k>>3)+16m, matching the C/D-layout register order of the
//             previous step's accumulator. MFMA contraction is order-agnostic
//             over k-slots, so the product is exactly T^T @ M.
//   Kernel 2: two waves per batch (split-chain, R6-proven). Per step:
//             8x v_cvt_pk_bf16_f32 DIRECTLY from acc regs (no permlane,
//             thanks to sigma-permutation) + 2x mfma_32x32x16_bf16;
//             2-deep fragment prefetch; acc pinned to ArchVGPRs via no-op asm.
// NOTE (R4/R5): __launch_bounds__(256,4)+readfirstlane+z-hoist bundle NaN'd;
// cause unisolated -- none of those edits are used here.

#define BATCH   4096
#define N_SITES 1024
#define NKEYS   256
#define NSTEP_H 64    // steps per wave (half chain)

typedef __attribute__((ext_vector_type(8)))  short    short8;
typedef __attribute__((ext_vector_type(16))) float    f32x16;
typedef __attribute__((ext_vector_type(4)))  unsigned uint4v;

// f32 -> bf16 RNE, bit-op version (table-build tail only)
static __device__ __forceinline__ unsigned short f32_to_bf16(float f) {
  unsigned u = __builtin_bit_cast(unsigned, f);
  const unsigned rounding = 0x7FFFu + ((u >> 16) & 1u);
  return (unsigned short)((u + rounding) >> 16);
}

// packed f32x2 -> bf16x2 in one VALU instruction (RNE; src0 -> low 16)
static __device__ __forceinline__ unsigned cvt_pk_bf16(float lo, float hi) {
  unsigned r;
  asm("v_cvt_pk_bf16_f32 %0, %1, %2" : "=v"(r) : "v"(lo), "v"(hi));
  return r;
}

// ---------------------------------------------------------------------------
// Kernel 1: table build. 256 blocks (one per key) x 256 threads.
// (R3/R6-proven body; only the fragment-store index uses the sigma permutation)
// ---------------------------------------------------------------------------
__global__ __launch_bounds__(256) void build_table_k(const float* __restrict__ A,
                                                     unsigned short* __restrict__ table) {
  __shared__ float As[2][32][32];
  __shared__ float M[2][32][32];
  const int key = blockIdx.x;
  const int t   = threadIdx.x;

  for (int i = t; i < 2 * 32 * 32; i += 256) ((float*)As)[i] = A[i];

  const int row = t >> 3;          // 0..31
  const int col = (t & 7) << 2;    // 0,4,...,28
  __syncthreads();

  {
    const int b0 = key & 1;
    const float4 v = *reinterpret_cast<const float4*>(&As[b0][row][col]);
    *reinterpret_cast<float4*>(&M[0][row][col]) = v;
  }
  __syncthreads();

  int cur = 0;
  for (int i = 1; i < 8; ++i) {
    const int bi = (key >> i) & 1;
    float a0 = 0.f, a1 = 0.f, a2 = 0.f, a3 = 0.f;
    for (int k = 0; k < 32; ++k) {
      const float m  = M[cur][row][k];
      const float4 v = *reinterpret_cast<const float4*>(&As[bi][k][col]);
      a0 += m * v.x; a1 += m * v.y; a2 += m * v.z; a3 += m * v.w;
    }
    M[cur ^ 1][row][col + 0] = a0;
    M[cur ^ 1][row][col + 1] = a1;
    M[cur ^ 1][row][col + 2] = a2;
    M[cur ^ 1][row][col + 3] = a3;
    __syncthreads();
    cur ^= 1;
  }

  // bf16 entry, A-fragment layout of T^T with sigma-permuted k-slots:
  //   MFMA c, lane l (rowm=l&31, hi=l>>5), elem ee=0..7:
  //     sg = (ee&3) + 8*(ee>>2) + 4*hi + 16*c ;  value = T[sg][rowm]
  //   ushort offset: key*1024 + c*512 + l*8 + ee
  const int c    = t >> 7;         // 0..1
  const int l    = (t >> 1) & 63;  // lane
  const int e4   = (t & 1) << 2;   // 0 or 4
  const int rowm = l & 31;
  const int hi   = l >> 5;

  unsigned long long packed = 0;
  for (int e = 0; e < 4; ++e) {
    const int ee = e4 + e;
    const int sg = (ee & 3) + ((ee >> 2) << 3) + (hi << 2) + (c << 4);
    const unsigned short us = f32_to_bf16(M[cur][sg][rowm]);
    packed |= (unsigned long long)us << (16 * e);
  }
  *reinterpret_cast<unsigned long long*>(table + (size_t)key * 1024 + c * 512 + l * 8 + e4) = packed;
}

// ---------------------------------------------------------------------------
// Kernel 2: split-chain contraction. 2048 blocks x 256 threads.
// Block = 2 pairs; pair = 2 waves; each wave does 64 steps of one batch chain.
// ---------------------------------------------------------------------------
__global__ __launch_bounds__(256) void mps_chain_k(const float* __restrict__ s,
                                                   const unsigned short* __restrict__ table,
                                                   float* __restrict__ out) {
  const int t    = threadIdx.x;
  const int pair = t >> 7;          // 0..1   (which batch within block)
  const int wv   = (t >> 6) & 1;    // 0..1   (which half of the chain)
  const int lane = t & 63;
  const int b    = blockIdx.x * 2 + pair;

  __shared__ unsigned char keys[2][128 + 8];   // per pair, padded for j+3 prefetch reads
  __shared__ float Ht[2][1024];                // wave1's product, transposed+rotated

  // --- key extraction: one key (8 sites) per lane; kidx = wv*64+lane
  const int kidx = wv * 64 + lane;
  const float4* s4 = reinterpret_cast<const float4*>(s) + (size_t)b * 256 + kidx * 2;
  const float4 va = s4[0];
  const float4 vb = s4[1];
  const unsigned key =
      (va.x > 0.f ? 1u : 0u)  | (va.y > 0.f ? 2u : 0u)  |
      (va.z > 0.f ? 4u : 0u)  | (va.w > 0.f ? 8u : 0u)  |
      (vb.x > 0.f ? 16u : 0u) | (vb.y > 0.f ? 32u : 0u) |
      (vb.z > 0.f ? 64u : 0u) | (vb.w > 0.f ? 128u : 0u);
  keys[pair][kidx] = (unsigned char)key;
  if (t < 16) keys[t >> 3][128 + (t & 7)] = 0;   // zero the pad region
  __syncthreads();

  const int col = lane & 31;
  const int hi  = lane >> 5;

  // carry = I in 32x32 C-layout: acc[r] = M[(r&3)+8*(r>>2)+4*hi][col]
  f32x16 acc;
#pragma unroll
  for (int r = 0; r < 16; ++r) {
    const int rr = (r & 3) + 8 * (r >> 2) + 4 * hi;
    acc[r] = (rr == col) ? 1.f : 0.f;
  }

  const unsigned char* kw = keys[pair] + wv * NSTEP_H;
  const unsigned long long laneoff = (unsigned long long)lane * 8;

  // 2-deep fragment prefetch pipeline (R6-proven form)
  unsigned kA = kw[0], kB = kw[1];
  unsigned kC = kw[2];                              // key for step j+2
  const unsigned short* e0 = table + (size_t)kA * 1024;
  const unsigned short* e1 = table + (size_t)kB * 1024;
  uint4v c0 = *reinterpret_cast<const uint4v*>(e0 + laneoff);
  uint4v c1 = *reinterpret_cast<const uint4v*>(e0 + 512 + laneoff);
  uint4v n0 = *reinterpret_cast<const uint4v*>(e1 + laneoff);
  uint4v n1 = *reinterpret_cast<const uint4v*>(e1 + 512 + laneoff);

#pragma unroll 4
  for (int j = 0; j < NSTEP_H; ++j) {
    // issue loads for step j+2
    const unsigned short* ef = table + ((size_t)kC << 10);
    const uint4v f0 = *reinterpret_cast<const uint4v*>(ef + laneoff);
    const uint4v f1 = *reinterpret_cast<const uint4v*>(ef + 512 + laneoff);
    kC = kw[j + 3];

    // carry (f32, C-layout) -> bf16 B fragments, DIRECT pairing (sigma-permuted
    // table makes B-slot order == acc register order): 8 cvt_pk, no permlane.
    union { unsigned u[4]; short8 v; } B1, B2;
#pragma unroll
    for (int i = 0; i < 4; ++i) {
      B1.u[i] = cvt_pk_bf16(acc[2 * i],     acc[2 * i + 1]);
      B2.u[i] = cvt_pk_bf16(acc[8 + 2 * i], acc[9 + 2 * i]);
    }

    union { uint4v q; short8 v; } ua0, ua1;
    ua0.q = c0; ua1.q = c1;

    f32x16 z;
#pragma unroll
    for (int r = 0; r < 16; ++r) z[r] = 0.f;

    f32x16 t1 = __builtin_amdgcn_mfma_f32_32x32x16_bf16(ua0.v, B1.v, z, 0, 0, 0);
    acc = __builtin_amdgcn_mfma_f32_32x32x16_bf16(ua1.v, B2.v, t1, 0, 0, 0);
    // pin loop-carried accumulator to ArchVGPRs (no-op asm; allocation hint
    // to prevent AGPR ping-pong around the cvt_pk reads)
    asm("" : "+v"(acc));

    // rotate pipeline
    c0 = n0; c1 = n1; n0 = f0; n1 = f1;
  }

  // --- combine: M^T = H @ L (H = wave1 partial, L = wave0 partial)
  // trace(H@L) = sum_{i,k} H[i,k] * L[k,i].
  // Wave1 stores element H[a][b] (a=row(r,lane), b=col) at Ht[b*32 + ((a+b)&31)]
  // (rotation keeps both write and read conflict-free).
  if (wv == 1) {
#pragma unroll
    for (int r = 0; r < 16; ++r) {
      const int a = (r & 3) + 8 * (r >> 2) + 4 * hi;
      Ht[pair][col * 32 + ((a + col) & 31)] = acc[r];
    }
  }
  __syncthreads();
  if (wv == 0) {
    float dot = 0.f;
#pragma unroll
    for (int r = 0; r < 16; ++r) {
      const int k = (r & 3) + 8 * (r >> 2) + 4 * hi;   // L-element row
      // need H[i=col][k]: stored at Ht[k*32 + ((col+k)&31)]
      dot += acc[r] * Ht[pair][k * 32 + ((col + k) & 31)];
    }
#pragma unroll
    for (int off = 32; off > 0; off >>= 1) dot += __shfl_down(dot, off, 64);
    if (lane == 0) out[b] = logf(dot);
  }
}

// ---------------------------------------------------------------------------
extern "C" void kernel_launch(void* const* d_in, const int* in_sizes, int n_in,
                              void* d_out, int out_size, void* d_ws, size_t ws_size,
                              hipStream_t stream) {
  const float* s = (const float*)d_in[0];   // [4096,1024] f32
  const float* A = (const float*)d_in[1];   // [2,32,32] f32
  float* out = (float*)d_out;               // [4096] f32
  unsigned short* table = (unsigned short*)d_ws;  // 256 * 2048 B = 512 KiB

  build_table_k<<<NKEYS, 256, 0, stream>>>(A, table);
  mps_chain_k<<<BATCH / 2, 256, 0, stream>>>(s, table, out);
}

// Round 8
// 116.399 us; speedup vs baseline: 1.0195x; 1.0195x over previous
//
#include <hip/hip_runtime.h>
#include <hip/hip_bf16.h>

// MPS log-trace: out[b] = log(trace(prod_{n=0..1023} A[s_idx[b,n]]))
//   Kernel 1: 256-entry table T[key] = A[b0]@...@A[b7] (fp32 in LDS), stored
//             bf16 as MFMA A-fragments with SIGMA-PERMUTED k-slots (R7-proven):
//             slot k of MFMA m carries logical row sg=(k&3)+8*((k>>2)&1)+4*(k>>3)+16m,
//             matching the C/D accumulator register order -> direct cvt_pk, no permlane.
//   Kernel 2: ILP-2 split-chain. Each wave runs the SAME half (lo/hi) of TWO
//             different batches as independent streams A/B (hides MFMA/load
//             latency). Block = 4 waves = 4 batches. Combine: M^T = H@L,
//             trace = sum H[i,k]*L[k,i] via rotated-transpose LDS (R6-proven).
// NOTE (R4/R5): __launch_bounds__(256,4)+readfirstlane+z-hoist bundle NaN'd;
// cause unisolated -- none of those edits are used here.

#define BATCH   4096
#define N_SITES 1024
#define NKEYS   256
#define NSTEP_H 64    // steps per wave per stream (half chain)

typedef __attribute__((ext_vector_type(8)))  short    short8;
typedef __attribute__((ext_vector_type(16))) float    f32x16;
typedef __attribute__((ext_vector_type(4)))  unsigned uint4v;

// f32 -> bf16 RNE, bit-op version (table-build tail only)
static __device__ __forceinline__ unsigned short f32_to_bf16(float f) {
  unsigned u = __builtin_bit_cast(unsigned, f);
  const unsigned rounding = 0x7FFFu + ((u >> 16) & 1u);
  return (unsigned short)((u + rounding) >> 16);
}

// packed f32x2 -> bf16x2 in one VALU instruction (RNE; src0 -> low 16)
static __device__ __forceinline__ unsigned cvt_pk_bf16(float lo, float hi) {
  unsigned r;
  asm("v_cvt_pk_bf16_f32 %0, %1, %2" : "=v"(r) : "v"(lo), "v"(hi));
  return r;
}

// ---------------------------------------------------------------------------
// Kernel 1: table build. 256 blocks (one per key) x 256 threads. (R7-proven)
// ---------------------------------------------------------------------------
__global__ __launch_bounds__(256) void build_table_k(const float* __restrict__ A,
                                                     unsigned short* __restrict__ table) {
  __shared__ float As[2][32][32];
  __shared__ float M[2][32][32];
  const int key = blockIdx.x;
  const int t   = threadIdx.x;

  for (int i = t; i < 2 * 32 * 32; i += 256) ((float*)As)[i] = A[i];

  const int row = t >> 3;          // 0..31
  const int col = (t & 7) << 2;    // 0,4,...,28
  __syncthreads();

  {
    const int b0 = key & 1;
    const float4 v = *reinterpret_cast<const float4*>(&As[b0][row][col]);
    *reinterpret_cast<float4*>(&M[0][row][col]) = v;
  }
  __syncthreads();

  int cur = 0;
  for (int i = 1; i < 8; ++i) {
    const int bi = (key >> i) & 1;
    float a0 = 0.f, a1 = 0.f, a2 = 0.f, a3 = 0.f;
    for (int k = 0; k < 32; ++k) {
      const float m  = M[cur][row][k];
      const float4 v = *reinterpret_cast<const float4*>(&As[bi][k][col]);
      a0 += m * v.x; a1 += m * v.y; a2 += m * v.z; a3 += m * v.w;
    }
    M[cur ^ 1][row][col + 0] = a0;
    M[cur ^ 1][row][col + 1] = a1;
    M[cur ^ 1][row][col + 2] = a2;
    M[cur ^ 1][row][col + 3] = a3;
    __syncthreads();
    cur ^= 1;
  }

  // bf16 entry, A-fragment layout of T^T with sigma-permuted k-slots:
  //   MFMA c, lane l (rowm=l&31, hi=l>>5), elem ee=0..7:
  //     sg = (ee&3) + 8*(ee>>2) + 4*hi + 16*c ;  value = T[sg][rowm]
  const int c    = t >> 7;         // 0..1
  const int l    = (t >> 1) & 63;  // lane
  const int e4   = (t & 1) << 2;   // 0 or 4
  const int rowm = l & 31;
  const int hi   = l >> 5;

  unsigned long long packed = 0;
  for (int e = 0; e < 4; ++e) {
    const int ee = e4 + e;
    const int sg = (ee & 3) + ((ee >> 2) << 3) + (hi << 2) + (c << 4);
    const unsigned short us = f32_to_bf16(M[cur][sg][rowm]);
    packed |= (unsigned long long)us << (16 * e);
  }
  *reinterpret_cast<unsigned long long*>(table + (size_t)key * 1024 + c * 512 + l * 8 + e4) = packed;
}

// ---------------------------------------------------------------------------
// Kernel 2: ILP-2 split-chain. 1024 blocks x 256 threads.
// Block = 4 batches. Wave w (0..3): half = w&1, batches bA = (w>>1)*2, bB = bA+1.
// ---------------------------------------------------------------------------
__global__ __launch_bounds__(256) void mps_chain_k(const float* __restrict__ s,
                                                   const unsigned short* __restrict__ table,
                                                   float* __restrict__ out) {
  const int t    = threadIdx.x;
  const int wave = t >> 6;          // 0..3
  const int lane = t & 63;
  const int half = wave & 1;        // 0 = low 64 steps, 1 = high 64 steps
  const int bA   = (wave >> 1) * 2; // local batch of stream A
  const int bB   = bA + 1;          // local batch of stream B

  __shared__ unsigned char keys[4][136];   // 128 keys + 8 pad per local batch
  __shared__ float Ht[4][1024];            // high-half products, transposed+rotated

  // --- key extraction: 512 keys per block, 2 per thread
#pragma unroll
  for (int g = t; g < 512; g += 256) {
    const int kb   = g >> 7;        // local batch 0..3
    const int kidx = g & 127;       // key index within chain
    const int bg   = blockIdx.x * 4 + kb;
    const float4* s4 = reinterpret_cast<const float4*>(s) + (size_t)bg * 256 + kidx * 2;
    const float4 va = s4[0];
    const float4 vb = s4[1];
    const unsigned key =
        (va.x > 0.f ? 1u : 0u)  | (va.y > 0.f ? 2u : 0u)  |
        (va.z > 0.f ? 4u : 0u)  | (va.w > 0.f ? 8u : 0u)  |
        (vb.x > 0.f ? 16u : 0u) | (vb.y > 0.f ? 32u : 0u) |
        (vb.z > 0.f ? 64u : 0u) | (vb.w > 0.f ? 128u : 0u);
    keys[kb][kidx] = (unsigned char)key;
  }
  if (t < 32) keys[t >> 3][128 + (t & 7)] = 0;   // zero pad region
  __syncthreads();

  const int col = lane & 31;
  const int hi  = lane >> 5;

  // carry = I in 32x32 C-layout: acc[r] = M[(r&3)+8*(r>>2)+4*hi][col]
  f32x16 accA, accB;
#pragma unroll
  for (int r = 0; r < 16; ++r) {
    const int rr = (r & 3) + 8 * (r >> 2) + 4 * hi;
    const float v = (rr == col) ? 1.f : 0.f;
    accA[r] = v; accB[r] = v;
  }

  const unsigned char* kwA = &keys[bA][half * NSTEP_H];
  const unsigned char* kwB = &keys[bB][half * NSTEP_H];
  const unsigned long long laneoff = (unsigned long long)lane * 8;

  // 2-deep fragment prefetch pipelines, one per stream
  const unsigned short* eA0 = table + ((size_t)kwA[0] << 10);
  const unsigned short* eA1 = table + ((size_t)kwA[1] << 10);
  const unsigned short* eB0 = table + ((size_t)kwB[0] << 10);
  const unsigned short* eB1 = table + ((size_t)kwB[1] << 10);
  unsigned kCA = kwA[2], kCB = kwB[2];
  uint4v cA0 = *reinterpret_cast<const uint4v*>(eA0 + laneoff);
  uint4v cA1 = *reinterpret_cast<const uint4v*>(eA0 + 512 + laneoff);
  uint4v nA0 = *reinterpret_cast<const uint4v*>(eA1 + laneoff);
  uint4v nA1 = *reinterpret_cast<const uint4v*>(eA1 + 512 + laneoff);
  uint4v cB0 = *reinterpret_cast<const uint4v*>(eB0 + laneoff);
  uint4v cB1 = *reinterpret_cast<const uint4v*>(eB0 + 512 + laneoff);
  uint4v nB0 = *reinterpret_cast<const uint4v*>(eB1 + laneoff);
  uint4v nB1 = *reinterpret_cast<const uint4v*>(eB1 + 512 + laneoff);

#pragma unroll 2
  for (int j = 0; j < NSTEP_H; ++j) {
    // issue loads for step j+2, both streams
    const unsigned short* efA = table + ((size_t)kCA << 10);
    const uint4v fA0 = *reinterpret_cast<const uint4v*>(efA + laneoff);
    const uint4v fA1 = *reinterpret_cast<const uint4v*>(efA + 512 + laneoff);
    kCA = kwA[j + 3];
    const unsigned short* efB = table + ((size_t)kCB << 10);
    const uint4v fB0 = *reinterpret_cast<const uint4v*>(efB + laneoff);
    const uint4v fB1 = *reinterpret_cast<const uint4v*>(efB + 512 + laneoff);
    kCB = kwB[j + 3];

    f32x16 z;
#pragma unroll
    for (int r = 0; r < 16; ++r) z[r] = 0.f;

    // stream A: acc -> bf16 B fragments (direct pairing, sigma table), 2 MFMA
    union { unsigned u[4]; short8 v; } BA1, BA2, BB1, BB2;
#pragma unroll
    for (int i = 0; i < 4; ++i) {
      BA1.u[i] = cvt_pk_bf16(accA[2 * i],     accA[2 * i + 1]);
      BA2.u[i] = cvt_pk_bf16(accA[8 + 2 * i], accA[9 + 2 * i]);
      BB1.u[i] = cvt_pk_bf16(accB[2 * i],     accB[2 * i + 1]);
      BB2.u[i] = cvt_pk_bf16(accB[8 + 2 * i], accB[9 + 2 * i]);
    }

    union { uint4v q; short8 v; } uA0, uA1, uB0, uB1;
    uA0.q = cA0; uA1.q = cA1; uB0.q = cB0; uB1.q = cB1;

    f32x16 tA = __builtin_amdgcn_mfma_f32_32x32x16_bf16(uA0.v, BA1.v, z, 0, 0, 0);
    f32x16 tB = __builtin_amdgcn_mfma_f32_32x32x16_bf16(uB0.v, BB1.v, z, 0, 0, 0);
    accA = __builtin_amdgcn_mfma_f32_32x32x16_bf16(uA1.v, BA2.v, tA, 0, 0, 0);
    accB = __builtin_amdgcn_mfma_f32_32x32x16_bf16(uB1.v, BB2.v, tB, 0, 0, 0);

    // rotate pipelines
    cA0 = nA0; cA1 = nA1; nA0 = fA0; nA1 = fA1;
    cB0 = nB0; cB1 = nB1; nB0 = fB0; nB1 = fB1;
  }

  // --- combine: M^T = H @ L; trace(H@L) = sum H[i,k]*L[k,i].
  // High wave stores H[a][b] at Ht[b*32 + ((a+b)&31)] (conflict-free rotation).
  if (half == 1) {
#pragma unroll
    for (int r = 0; r < 16; ++r) {
      const int a = (r & 3) + 8 * (r >> 2) + 4 * hi;
      const int slot = col * 32 + ((a + col) & 31);
      Ht[bA][slot] = accA[r];
      Ht[bB][slot] = accB[r];
    }
  }
  __syncthreads();
  if (half == 0) {
    float d0 = 0.f, d1 = 0.f;
#pragma unroll
    for (int r = 0; r < 16; ++r) {
      const int k = (r & 3) + 8 * (r >> 2) + 4 * hi;   // L-element row
      const int slot = k * 32 + ((col + k) & 31);      // H[i=col][k]
      d0 += accA[r] * Ht[bA][slot];
      d1 += accB[r] * Ht[bB][slot];
    }
#pragma unroll
    for (int off = 32; off > 0; off >>= 1) {
      d0 += __shfl_down(d0, off, 64);
      d1 += __shfl_down(d1, off, 64);
    }
    if (lane == 0) {
      out[blockIdx.x * 4 + bA] = logf(d0);
      out[blockIdx.x * 4 + bB] = logf(d1);
    }
  }
}

// ---------------------------------------------------------------------------
extern "C" void kernel_launch(void* const* d_in, const int* in_sizes, int n_in,
                              void* d_out, int out_size, void* d_ws, size_t ws_size,
                              hipStream_t stream) {
  const float* s = (const float*)d_in[0];   // [4096,1024] f32
  const float* A = (const float*)d_in[1];   // [2,32,32] f32
  float* out = (float*)d_out;               // [4096] f32
  unsigned short* table = (unsigned short*)d_ws;  // 256 * 2048 B = 512 KiB

  build_table_k<<<NKEYS, 256, 0, stream>>>(A, table);
  mps_chain_k<<<BATCH / 4, 256, 0, stream>>>(s, table, out);
}

// Round 9
// 109.004 us; speedup vs baseline: 1.0887x; 1.0678x over previous
//
#include <hip/hip_runtime.h>
#include <hip/hip_bf16.h>

// MPS log-trace: out[b] = log(trace(prod_{n=0..1023} A[s_idx[b,n]]))
//   Kernel 1: 256-entry table T[key] = A[b0]@...@A[b7] (fp32 in LDS), stored
//             bf16 as MFMA A-fragments with SIGMA-PERMUTED k-slots (R7-proven):
//             slot k of MFMA m carries logical row sg=(k&3)+8*((k>>2)&1)+4*(k>>3)+16m,
//             matching the C/D accumulator register order -> direct cvt_pk, no permlane.
//   Kernel 2: ILP-2 split-chain (R8-proven structure) + __launch_bounds__(256,4)
//             to force ArchVGPR allocation (R8 PMC: VGPR=48 => acc in AGPRs =>
//             ~86 extra v_accvgpr/mov per wave-iter = measured 121 vs ~35 essential).
//             1-deep per-stream prefetch (fits the 128-reg budget; ~600cyc slack
//             vs ~250cyc L2 latency).
// R4/R5 NaN bisect: this round reintroduces ONLY __launch_bounds__(256,4) from
// that bundle (no readfirstlane, no z-hoist beyond what R8 already had).

#define BATCH   4096
#define N_SITES 1024
#define NKEYS   256
#define NSTEP_H 64    // steps per wave per stream (half chain)

typedef __attribute__((ext_vector_type(8)))  short    short8;
typedef __attribute__((ext_vector_type(16))) float    f32x16;
typedef __attribute__((ext_vector_type(4)))  unsigned uint4v;

// f32 -> bf16 RNE, bit-op version (table-build tail only)
static __device__ __forceinline__ unsigned short f32_to_bf16(float f) {
  unsigned u = __builtin_bit_cast(unsigned, f);
  const unsigned rounding = 0x7FFFu + ((u >> 16) & 1u);
  return (unsigned short)((u + rounding) >> 16);
}

// packed f32x2 -> bf16x2 in one VALU instruction (RNE; src0 -> low 16)
static __device__ __forceinline__ unsigned cvt_pk_bf16(float lo, float hi) {
  unsigned r;
  asm("v_cvt_pk_bf16_f32 %0, %1, %2" : "=v"(r) : "v"(lo), "v"(hi));
  return r;
}

// ---------------------------------------------------------------------------
// Kernel 1: table build. 256 blocks (one per key) x 256 threads. (R7-proven)
// ---------------------------------------------------------------------------
__global__ __launch_bounds__(256) void build_table_k(const float* __restrict__ A,
                                                     unsigned short* __restrict__ table) {
  __shared__ float As[2][32][32];
  __shared__ float M[2][32][32];
  const int key = blockIdx.x;
  const int t   = threadIdx.x;

  for (int i = t; i < 2 * 32 * 32; i += 256) ((float*)As)[i] = A[i];

  const int row = t >> 3;          // 0..31
  const int col = (t & 7) << 2;    // 0,4,...,28
  __syncthreads();

  {
    const int b0 = key & 1;
    const float4 v = *reinterpret_cast<const float4*>(&As[b0][row][col]);
    *reinterpret_cast<float4*>(&M[0][row][col]) = v;
  }
  __syncthreads();

  int cur = 0;
  for (int i = 1; i < 8; ++i) {
    const int bi = (key >> i) & 1;
    float a0 = 0.f, a1 = 0.f, a2 = 0.f, a3 = 0.f;
    for (int k = 0; k < 32; ++k) {
      const float m  = M[cur][row][k];
      const float4 v = *reinterpret_cast<const float4*>(&As[bi][k][col]);
      a0 += m * v.x; a1 += m * v.y; a2 += m * v.z; a3 += m * v.w;
    }
    M[cur ^ 1][row][col + 0] = a0;
    M[cur ^ 1][row][col + 1] = a1;
    M[cur ^ 1][row][col + 2] = a2;
    M[cur ^ 1][row][col + 3] = a3;
    __syncthreads();
    cur ^= 1;
  }

  // bf16 entry, A-fragment layout of T^T with sigma-permuted k-slots:
  //   MFMA c, lane l (rowm=l&31, hi=l>>5), elem ee=0..7:
  //     sg = (ee&3) + 8*(ee>>2) + 4*hi + 16*c ;  value = T[sg][rowm]
  const int c    = t >> 7;         // 0..1
  const int l    = (t >> 1) & 63;  // lane
  const int e4   = (t & 1) << 2;   // 0 or 4
  const int rowm = l & 31;
  const int hi   = l >> 5;

  unsigned long long packed = 0;
  for (int e = 0; e < 4; ++e) {
    const int ee = e4 + e;
    const int sg = (ee & 3) + ((ee >> 2) << 3) + (hi << 2) + (c << 4);
    const unsigned short us = f32_to_bf16(M[cur][sg][rowm]);
    packed |= (unsigned long long)us << (16 * e);
  }
  *reinterpret_cast<unsigned long long*>(table + (size_t)key * 1024 + c * 512 + l * 8 + e4) = packed;
}

// ---------------------------------------------------------------------------
// Kernel 2: ILP-2 split-chain. 1024 blocks x 256 threads.
// Block = 4 batches. Wave w (0..3): half = w&1, batches bA = (w>>1)*2, bB = bA+1.
// ---------------------------------------------------------------------------
__global__ __launch_bounds__(256, 4) void mps_chain_k(const float* __restrict__ s,
                                                      const unsigned short* __restrict__ table,
                                                      float* __restrict__ out) {
  const int t    = threadIdx.x;
  const int wave = t >> 6;          // 0..3
  const int lane = t & 63;
  const int half = wave & 1;        // 0 = low 64 steps, 1 = high 64 steps
  const int bA   = (wave >> 1) * 2; // local batch of stream A
  const int bB   = bA + 1;          // local batch of stream B

  __shared__ unsigned char keys[4][136];   // 128 keys + 8 pad per local batch
  __shared__ float Ht[4][1024];            // high-half products, transposed+rotated

  // --- key extraction: 512 keys per block, 2 per thread
#pragma unroll
  for (int g = t; g < 512; g += 256) {
    const int kb   = g >> 7;        // local batch 0..3
    const int kidx = g & 127;       // key index within chain
    const int bg   = blockIdx.x * 4 + kb;
    const float4* s4 = reinterpret_cast<const float4*>(s) + (size_t)bg * 256 + kidx * 2;
    const float4 va = s4[0];
    const float4 vb = s4[1];
    const unsigned key =
        (va.x > 0.f ? 1u : 0u)  | (va.y > 0.f ? 2u : 0u)  |
        (va.z > 0.f ? 4u : 0u)  | (va.w > 0.f ? 8u : 0u)  |
        (vb.x > 0.f ? 16u : 0u) | (vb.y > 0.f ? 32u : 0u) |
        (vb.z > 0.f ? 64u : 0u) | (vb.w > 0.f ? 128u : 0u);
    keys[kb][kidx] = (unsigned char)key;
  }
  if (t < 32) keys[t >> 3][128 + (t & 7)] = 0;   // zero pad region
  __syncthreads();

  const int col = lane & 31;
  const int hi  = lane >> 5;

  // carry = I in 32x32 C-layout: acc[r] = M[(r&3)+8*(r>>2)+4*hi][col]
  f32x16 accA, accB;
#pragma unroll
  for (int r = 0; r < 16; ++r) {
    const int rr = (r & 3) + 8 * (r >> 2) + 4 * hi;
    const float v = (rr == col) ? 1.f : 0.f;
    accA[r] = v; accB[r] = v;
  }

  const unsigned char* kwA = &keys[bA][half * NSTEP_H];
  const unsigned char* kwB = &keys[bB][half * NSTEP_H];
  const unsigned long long laneoff = (unsigned long long)lane * 8;

  // 1-deep per-stream fragment prefetch (fits 128-reg budget)
  const unsigned short* eA = table + ((size_t)kwA[0] << 10);
  const unsigned short* eB = table + ((size_t)kwB[0] << 10);
  uint4v cA0 = *reinterpret_cast<const uint4v*>(eA + laneoff);
  uint4v cA1 = *reinterpret_cast<const uint4v*>(eA + 512 + laneoff);
  uint4v cB0 = *reinterpret_cast<const uint4v*>(eB + laneoff);
  uint4v cB1 = *reinterpret_cast<const uint4v*>(eB + 512 + laneoff);
  unsigned kNA = kwA[1], kNB = kwB[1];   // key for step j+1

#pragma unroll 2
  for (int j = 0; j < NSTEP_H; ++j) {
    // issue loads for step j+1, both streams
    const unsigned short* efA = table + ((size_t)kNA << 10);
    const uint4v fA0 = *reinterpret_cast<const uint4v*>(efA + laneoff);
    const uint4v fA1 = *reinterpret_cast<const uint4v*>(efA + 512 + laneoff);
    const unsigned short* efB = table + ((size_t)kNB << 10);
    const uint4v fB0 = *reinterpret_cast<const uint4v*>(efB + laneoff);
    const uint4v fB1 = *reinterpret_cast<const uint4v*>(efB + 512 + laneoff);
    kNA = kwA[j + 2];                    // pad keeps j=62,63 reads in-bounds
    kNB = kwB[j + 2];

    f32x16 z;
#pragma unroll
    for (int r = 0; r < 16; ++r) z[r] = 0.f;

    // acc -> bf16 B fragments (direct pairing via sigma table), 8 cvt_pk/stream
    union { unsigned u[4]; short8 v; } BA1, BA2, BB1, BB2;
#pragma unroll
    for (int i = 0; i < 4; ++i) {
      BA1.u[i] = cvt_pk_bf16(accA[2 * i],     accA[2 * i + 1]);
      BA2.u[i] = cvt_pk_bf16(accA[8 + 2 * i], accA[9 + 2 * i]);
      BB1.u[i] = cvt_pk_bf16(accB[2 * i],     accB[2 * i + 1]);
      BB2.u[i] = cvt_pk_bf16(accB[8 + 2 * i], accB[9 + 2 * i]);
    }

    union { uint4v q; short8 v; } uA0, uA1, uB0, uB1;
    uA0.q = cA0; uA1.q = cA1; uB0.q = cB0; uB1.q = cB1;

    f32x16 tA = __builtin_amdgcn_mfma_f32_32x32x16_bf16(uA0.v, BA1.v, z, 0, 0, 0);
    f32x16 tB = __builtin_amdgcn_mfma_f32_32x32x16_bf16(uB0.v, BB1.v, z, 0, 0, 0);
    accA = __builtin_amdgcn_mfma_f32_32x32x16_bf16(uA1.v, BA2.v, tA, 0, 0, 0);
    accB = __builtin_amdgcn_mfma_f32_32x32x16_bf16(uB1.v, BB2.v, tB, 0, 0, 0);

    // rotate pipelines
    cA0 = fA0; cA1 = fA1; cB0 = fB0; cB1 = fB1;
  }

  // --- combine: M^T = H @ L; trace(H@L) = sum H[i,k]*L[k,i].
  // High wave stores H[a][b] at Ht[b*32 + ((a+b)&31)] (conflict-free rotation).
  if (half == 1) {
#pragma unroll
    for (int r = 0; r < 16; ++r) {
      const int a = (r & 3) + 8 * (r >> 2) + 4 * hi;
      const int slot = col * 32 + ((a + col) & 31);
      Ht[bA][slot] = accA[r];
      Ht[bB][slot] = accB[r];
    }
  }
  __syncthreads();
  if (half == 0) {
    float d0 = 0.f, d1 = 0.f;
#pragma unroll
    for (int r = 0; r < 16; ++r) {
      const int k = (r & 3) + 8 * (r >> 2) + 4 * hi;   // L-element row
      const int slot = k * 32 + ((col + k) & 31);      // H[i=col][k]
      d0 += accA[r] * Ht[bA][slot];
      d1 += accB[r] * Ht[bB][slot];
    }
#pragma unroll
    for (int off = 32; off > 0; off >>= 1) {
      d0 += __shfl_down(d0, off, 64);
      d1 += __shfl_down(d1, off, 64);
    }
    if (lane == 0) {
      out[blockIdx.x * 4 + bA] = logf(d0);
      out[blockIdx.x * 4 + bB] = logf(d1);
    }
  }
}

// ---------------------------------------------------------------------------
extern "C" void kernel_launch(void* const* d_in, const int* in_sizes, int n_in,
                              void* d_out, int out_size, void* d_ws, size_t ws_size,
                              hipStream_t stream) {
  const float* s = (const float*)d_in[0];   // [4096,1024] f32
  const float* A = (const float*)d_in[1];   // [2,32,32] f32
  float* out = (float*)d_out;               // [4096] f32
  unsigned short* table = (unsigned short*)d_ws;  // 256 * 2048 B = 512 KiB

  build_table_k<<<NKEYS, 256, 0, stream>>>(A, table);
  mps_chain_k<<<BATCH / 4, 256, 0, stream>>>(s, table, out);
}

// Round 10
// 108.654 us; speedup vs baseline: 1.0922x; 1.0032x over previous
//
#include <hip/hip_runtime.h>
#include <hip/hip_bf16.h>

// MPS log-trace: out[b] = log(trace(prod_{n=0..1023} A[s_idx[b,n]]))
//   Kernel 1: 256-entry table T[key] = A[b0]@...@A[b7] (fp32 in LDS), stored
//             bf16 as MFMA A-fragments with SIGMA-PERMUTED k-slots (R7-proven):
//             slot k of MFMA m carries logical row sg=(k&3)+8*((k>>2)&1)+4*(k>>3)+16m,
//             matching the C/D accumulator register order -> direct cvt_pk, no permlane.
//   Kernel 2: ILP-2 split-chain + __launch_bounds__(256,4) (R9-proven: kills
//             AGPR ping-pong; VALUBusy 44->26%) + 2-DEEP per-stream prefetch
//             (R9 PMC: both pipes <30%, latency-exposed; 1-deep issue-to-use
//             distance ~450cyc ~= loaded L2 latency. 2-deep doubles it.)
// NaN bisect ledger: launch_bounds(256,4) exonerated (R9 passed). readfirstlane
// and z-hoist remain quarantined.

#define BATCH   4096
#define N_SITES 1024
#define NKEYS   256
#define NSTEP_H 64    // steps per wave per stream (half chain)

typedef __attribute__((ext_vector_type(8)))  short    short8;
typedef __attribute__((ext_vector_type(16))) float    f32x16;
typedef __attribute__((ext_vector_type(4)))  unsigned uint4v;

// f32 -> bf16 RNE, bit-op version (table-build tail only)
static __device__ __forceinline__ unsigned short f32_to_bf16(float f) {
  unsigned u = __builtin_bit_cast(unsigned, f);
  const unsigned rounding = 0x7FFFu + ((u >> 16) & 1u);
  return (unsigned short)((u + rounding) >> 16);
}

// packed f32x2 -> bf16x2 in one VALU instruction (RNE; src0 -> low 16)
static __device__ __forceinline__ unsigned cvt_pk_bf16(float lo, float hi) {
  unsigned r;
  asm("v_cvt_pk_bf16_f32 %0, %1, %2" : "=v"(r) : "v"(lo), "v"(hi));
  return r;
}

// ---------------------------------------------------------------------------
// Kernel 1: table build. 256 blocks (one per key) x 256 threads. (R7-proven)
// ---------------------------------------------------------------------------
__global__ __launch_bounds__(256) void build_table_k(const float* __restrict__ A,
                                                     unsigned short* __restrict__ table) {
  __shared__ float As[2][32][32];
  __shared__ float M[2][32][32];
  const int key = blockIdx.x;
  const int t   = threadIdx.x;

  for (int i = t; i < 2 * 32 * 32; i += 256) ((float*)As)[i] = A[i];

  const int row = t >> 3;          // 0..31
  const int col = (t & 7) << 2;    // 0,4,...,28
  __syncthreads();

  {
    const int b0 = key & 1;
    const float4 v = *reinterpret_cast<const float4*>(&As[b0][row][col]);
    *reinterpret_cast<float4*>(&M[0][row][col]) = v;
  }
  __syncthreads();

  int cur = 0;
  for (int i = 1; i < 8; ++i) {
    const int bi = (key >> i) & 1;
    float a0 = 0.f, a1 = 0.f, a2 = 0.f, a3 = 0.f;
    for (int k = 0; k < 32; ++k) {
      const float m  = M[cur][row][k];
      const float4 v = *reinterpret_cast<const float4*>(&As[bi][k][col]);
      a0 += m * v.x; a1 += m * v.y; a2 += m * v.z; a3 += m * v.w;
    }
    M[cur ^ 1][row][col + 0] = a0;
    M[cur ^ 1][row][col + 1] = a1;
    M[cur ^ 1][row][col + 2] = a2;
    M[cur ^ 1][row][col + 3] = a3;
    __syncthreads();
    cur ^= 1;
  }

  // bf16 entry, A-fragment layout of T^T with sigma-permuted k-slots:
  //   MFMA c, lane l (rowm=l&31, hi=l>>5), elem ee=0..7:
  //     sg = (ee&3) + 8*(ee>>2) + 4*hi + 16*c ;  value = T[sg][rowm]
  const int c    = t >> 7;         // 0..1
  const int l    = (t >> 1) & 63;  // lane
  const int e4   = (t & 1) << 2;   // 0 or 4
  const int rowm = l & 31;
  const int hi   = l >> 5;

  unsigned long long packed = 0;
  for (int e = 0; e < 4; ++e) {
    const int ee = e4 + e;
    const int sg = (ee & 3) + ((ee >> 2) << 3) + (hi << 2) + (c << 4);
    const unsigned short us = f32_to_bf16(M[cur][sg][rowm]);
    packed |= (unsigned long long)us << (16 * e);
  }
  *reinterpret_cast<unsigned long long*>(table + (size_t)key * 1024 + c * 512 + l * 8 + e4) = packed;
}

// ---------------------------------------------------------------------------
// Kernel 2: ILP-2 split-chain, 2-deep prefetch. 1024 blocks x 256 threads.
// Block = 4 batches. Wave w (0..3): half = w&1, batches bA = (w>>1)*2, bB = bA+1.
// ---------------------------------------------------------------------------
__global__ __launch_bounds__(256, 4) void mps_chain_k(const float* __restrict__ s,
                                                      const unsigned short* __restrict__ table,
                                                      float* __restrict__ out) {
  const int t    = threadIdx.x;
  const int wave = t >> 6;          // 0..3
  const int lane = t & 63;
  const int half = wave & 1;        // 0 = low 64 steps, 1 = high 64 steps
  const int bA   = (wave >> 1) * 2; // local batch of stream A
  const int bB   = bA + 1;          // local batch of stream B

  __shared__ unsigned char keys[4][136];   // 128 keys + 8 pad per local batch
  __shared__ float Ht[4][1024];            // high-half products, transposed+rotated

  // --- key extraction: 512 keys per block, 2 per thread
#pragma unroll
  for (int g = t; g < 512; g += 256) {
    const int kb   = g >> 7;        // local batch 0..3
    const int kidx = g & 127;       // key index within chain
    const int bg   = blockIdx.x * 4 + kb;
    const float4* s4 = reinterpret_cast<const float4*>(s) + (size_t)bg * 256 + kidx * 2;
    const float4 va = s4[0];
    const float4 vb = s4[1];
    const unsigned key =
        (va.x > 0.f ? 1u : 0u)  | (va.y > 0.f ? 2u : 0u)  |
        (va.z > 0.f ? 4u : 0u)  | (va.w > 0.f ? 8u : 0u)  |
        (vb.x > 0.f ? 16u : 0u) | (vb.y > 0.f ? 32u : 0u) |
        (vb.z > 0.f ? 64u : 0u) | (vb.w > 0.f ? 128u : 0u);
    keys[kb][kidx] = (unsigned char)key;
  }
  if (t < 32) keys[t >> 3][128 + (t & 7)] = 0;   // zero pad region
  __syncthreads();

  const int col = lane & 31;
  const int hi  = lane >> 5;

  // carry = I in 32x32 C-layout: acc[r] = M[(r&3)+8*(r>>2)+4*hi][col]
  f32x16 accA, accB;
#pragma unroll
  for (int r = 0; r < 16; ++r) {
    const int rr = (r & 3) + 8 * (r >> 2) + 4 * hi;
    const float v = (rr == col) ? 1.f : 0.f;
    accA[r] = v; accB[r] = v;
  }

  const unsigned char* kwA = &keys[bA][half * NSTEP_H];
  const unsigned char* kwB = &keys[bB][half * NSTEP_H];
  const unsigned long long laneoff = (unsigned long long)lane * 8;

  // 2-deep per-stream fragment prefetch
  const unsigned short* eA0 = table + ((size_t)kwA[0] << 10);
  const unsigned short* eA1 = table + ((size_t)kwA[1] << 10);
  const unsigned short* eB0 = table + ((size_t)kwB[0] << 10);
  const unsigned short* eB1 = table + ((size_t)kwB[1] << 10);
  unsigned kCA = kwA[2], kCB = kwB[2];
  uint4v cA0 = *reinterpret_cast<const uint4v*>(eA0 + laneoff);
  uint4v cA1 = *reinterpret_cast<const uint4v*>(eA0 + 512 + laneoff);
  uint4v nA0 = *reinterpret_cast<const uint4v*>(eA1 + laneoff);
  uint4v nA1 = *reinterpret_cast<const uint4v*>(eA1 + 512 + laneoff);
  uint4v cB0 = *reinterpret_cast<const uint4v*>(eB0 + laneoff);
  uint4v cB1 = *reinterpret_cast<const uint4v*>(eB0 + 512 + laneoff);
  uint4v nB0 = *reinterpret_cast<const uint4v*>(eB1 + laneoff);
  uint4v nB1 = *reinterpret_cast<const uint4v*>(eB1 + 512 + laneoff);

#pragma unroll 2
  for (int j = 0; j < NSTEP_H; ++j) {
    // issue loads for step j+2, both streams
    const unsigned short* efA = table + ((size_t)kCA << 10);
    const uint4v fA0 = *reinterpret_cast<const uint4v*>(efA + laneoff);
    const uint4v fA1 = *reinterpret_cast<const uint4v*>(efA + 512 + laneoff);
    kCA = kwA[j + 3];                    // pad keeps tail reads in-bounds
    const unsigned short* efB = table + ((size_t)kCB << 10);
    const uint4v fB0 = *reinterpret_cast<const uint4v*>(efB + laneoff);
    const uint4v fB1 = *reinterpret_cast<const uint4v*>(efB + 512 + laneoff);
    kCB = kwB[j + 3];

    f32x16 z;
#pragma unroll
    for (int r = 0; r < 16; ++r) z[r] = 0.f;

    // acc -> bf16 B fragments (direct pairing via sigma table), 8 cvt_pk/stream
    union { unsigned u[4]; short8 v; } BA1, BA2, BB1, BB2;
#pragma unroll
    for (int i = 0; i < 4; ++i) {
      BA1.u[i] = cvt_pk_bf16(accA[2 * i],     accA[2 * i + 1]);
      BA2.u[i] = cvt_pk_bf16(accA[8 + 2 * i], accA[9 + 2 * i]);
      BB1.u[i] = cvt_pk_bf16(accB[2 * i],     accB[2 * i + 1]);
      BB2.u[i] = cvt_pk_bf16(accB[8 + 2 * i], accB[9 + 2 * i]);
    }

    union { uint4v q; short8 v; } uA0, uA1, uB0, uB1;
    uA0.q = cA0; uA1.q = cA1; uB0.q = cB0; uB1.q = cB1;

    f32x16 tA = __builtin_amdgcn_mfma_f32_32x32x16_bf16(uA0.v, BA1.v, z, 0, 0, 0);
    f32x16 tB = __builtin_amdgcn_mfma_f32_32x32x16_bf16(uB0.v, BB1.v, z, 0, 0, 0);
    accA = __builtin_amdgcn_mfma_f32_32x32x16_bf16(uA1.v, BA2.v, tA, 0, 0, 0);
    accB = __builtin_amdgcn_mfma_f32_32x32x16_bf16(uB1.v, BB2.v, tB, 0, 0, 0);

    // rotate pipelines
    cA0 = nA0; cA1 = nA1; nA0 = fA0; nA1 = fA1;
    cB0 = nB0; cB1 = nB1; nB0 = fB0; nB1 = fB1;
  }

  // --- combine: M^T = H @ L; trace(H@L) = sum H[i,k]*L[k,i].
  // High wave stores H[a][b] at Ht[b*32 + ((a+b)&31)] (conflict-free rotation).
  if (half == 1) {
#pragma unroll
    for (int r = 0; r < 16; ++r) {
      const int a = (r & 3) + 8 * (r >> 2) + 4 * hi;
      const int slot = col * 32 + ((a + col) & 31);
      Ht[bA][slot] = accA[r];
      Ht[bB][slot] = accB[r];
    }
  }
  __syncthreads();
  if (half == 0) {
    float d0 = 0.f, d1 = 0.f;
#pragma unroll
    for (int r = 0; r < 16; ++r) {
      const int k = (r & 3) + 8 * (r >> 2) + 4 * hi;   // L-element row
      const int slot = k * 32 + ((col + k) & 31);      // H[i=col][k]
      d0 += accA[r] * Ht[bA][slot];
      d1 += accB[r] * Ht[bB][slot];
    }
#pragma unroll
    for (int off = 32; off > 0; off >>= 1) {
      d0 += __shfl_down(d0, off, 64);
      d1 += __shfl_down(d1, off, 64);
    }
    if (lane == 0) {
      out[blockIdx.x * 4 + bA] = logf(d0);
      out[blockIdx.x * 4 + bB] = logf(d1);
    }
  }
}

// ---------------------------------------------------------------------------
extern "C" void kernel_launch(void* const* d_in, const int* in_sizes, int n_in,
                              void* d_out, int out_size, void* d_ws, size_t ws_size,
                              hipStream_t stream) {
  const float* s = (const float*)d_in[0];   // [4096,1024] f32
  const float* A = (const float*)d_in[1];   // [2,32,32] f32
  float* out = (float*)d_out;               // [4096] f32
  unsigned short* table = (unsigned short*)d_ws;  // 256 * 2048 B = 512 KiB

  build_table_k<<<NKEYS, 256, 0, stream>>>(A, table);
  mps_chain_k<<<BATCH / 4, 256, 0, stream>>>(s, table, out);
}